// Round 11
// baseline (290.414 us; speedup 1.0000x reference)
//
#include <hip/hip_runtime.h>

// QNet forward, MI355X. Round 19 (= round 17 resubmitted; rounds 9-10 were
// GPU acquisition timeouts — kernel never ran. Audit standing: barriers
// uniform, bounds verified, LDS 100,608 <= 160K, no vmcnt asm, XS wave-
// private, dec phase verbatim from multiply-passed dec_kernel).
// FUSED enc+dec: one kernel, block = 16 rows x 32 agents (dec geometry),
// 8 waves, wave -> 4 agents. Enc phase: A-frags direct global->reg (no DMA,
// no slabs, no manual vmcnt), W1p/W2p B-frags streamed from L2 (2.1MB,
// L2-resident across 512 blocks, same pattern dec's Wcp always used);
// x-transpose via 4.4KB/wave LDS slab; h written directly into comm LDS
// layout. Deletes: hws 67MB roundtrip, dec staging, one launch, all enc
// pipeline machinery (3 structural variants of which were all neutral).
// pack: round-16 version (passed). B=8192, A=32, NOBS=128, NH1=128,
// HX=64, NACT=16. fp32 in/out.

#define NB   8192
#define NA   32
#define NOBS 128
#define NH1  128
#define HXX  64
#define NACT 16

typedef _Float16 half8 __attribute__((ext_vector_type(8)));
typedef _Float16 half4 __attribute__((ext_vector_type(4)));
typedef float    floatx4 __attribute__((ext_vector_type(4)));

#define MFMA16(af, bf, c) __builtin_amdgcn_mfma_f32_16x16x32_f16((af), (bf), (c), 0, 0, 0)

// ws offsets in halfs (hws region retained in layout but unused now)
#define HWS_OFF 0
#define W1P_OFF (NB * NA * HXX)                    // 16,777,216
#define W1P_CNT (NA * 8 * 4 * 512)                 // 524,288
#define W2P_OFF (W1P_OFF + W1P_CNT)
#define W2P_CNT (NA * 4 * 4 * 512)                 // 262,144
#define WCP_OFF (W2P_OFF + W2P_CNT)
#define WCP_CNT (NA * 4 * 4 * 512)                 // 262,144
#define WDP_OFF (WCP_OFF + WCP_CNT)
#define WDP_CNT (NA * 1 * 2 * 512)                 // 32,768
#define MN_OFF  (WDP_OFF + WDP_CNT)                // 17,858,560 (f32 x 1024)

#define HSTR 2056                                  // comm row slab (2048+8 pad)
#define FUS_SLAB 4352                              // 16x136 halfs per wave
#define FUS_LDS  (16 * HSTR * 2 + 8 * FUS_SLAB)    // 65,792 + 34,816 = 100,608

// pack geometry: 2112 frags (W1 1024, W2 512, Wc 512, Wd 64), 4 waves/block
#define PK_FRAG_BLOCKS 528
#define PK_BLOCKS      (PK_FRAG_BLOCKS + 4)        // +4 mask blocks (1024 thr)

__device__ __forceinline__ float fast_tanh(float x) {
    x = fminf(fmaxf(x, -10.f), 10.f);
    float e2 = __expf(2.f * x);
    return (e2 - 1.f) / (e2 + 1.f);
}

// ---------------------------------------------------------------------------
// Pack: fp32 weights -> f16 MFMA B-fragments; plus normalized comm mask (f32).
// frag(a,nt,s)[l*8+j] = W[a][s*32+(l>>4)*8+j][nt*16+(l&15)]
// One wave per fragment: stage 32x16 f32 sub-block to LDS (coalesced 64B
// segments), fence, emit fragment as one coalesced 1KB half8 store.
// ---------------------------------------------------------------------------
extern "C" __global__ __launch_bounds__(256)
void pack_kernel(const float* __restrict__ W1,
                 const float* __restrict__ W2,
                 const float* __restrict__ Wc,
                 const float* __restrict__ Wd,
                 const int*   __restrict__ cmask,
                 _Float16* __restrict__ ws)
{
    __shared__ float stg[4][512];
    const int bid = blockIdx.x, tid = threadIdx.x;

    if (bid >= PK_FRAG_BLOCKS) {                 // normalized mask -> f32
        int r = (bid - PK_FRAG_BLOCKS) * 256 + tid;
        if (r >= NA * NA) return;
        int i = r >> 5, j = r & 31;
        int c = 0;
        for (int jj = 0; jj < NA; ++jj) c += (jj != i && cmask[i * NA + jj]) ? 1 : 0;
        float v = 0.f;
        if (j != i && cmask[i * NA + j]) v = 1.0f / (float)(c > 1 ? c : 1);
        ((float*)(ws + MN_OFF))[r] = v;
        return;
    }

    const int w = tid >> 6, l = tid & 63;
    const int W = bid * 4 + w;                   // global fragment id, 0..2111

    const float* src; _Float16* dst; int K, N;
    int a, nt, s;
    if (W < 1024) {
        int q = W; a = q >> 5; nt = (q >> 2) & 7; s = q & 3;
        src = W1; N = 128; K = 128;
        dst = ws + W1P_OFF + ((a * 8 + nt) * 4 + s) * 512;
    } else if (W < 1536) {
        int q = W - 1024; a = q >> 4; nt = (q >> 2) & 3; s = q & 3;
        src = W2; N = 64; K = 128;
        dst = ws + W2P_OFF + ((a * 4 + nt) * 4 + s) * 512;
    } else if (W < 2048) {
        int q = W - 1536; a = q >> 4; nt = (q >> 2) & 3; s = q & 3;
        src = Wc; N = 64; K = 128;
        dst = ws + WCP_OFF + ((a * 4 + nt) * 4 + s) * 512;
    } else {
        int q = W - 2048; a = q >> 1; nt = 0; s = q & 1;
        src = Wd; N = 16; K = 64;
        dst = ws + WDP_OFF + (a * 2 + s) * 512;
    }

    const float* base = src + (size_t)a * K * N + (size_t)(s * 32) * N + nt * 16;
    float* S = stg[w];

    #pragma unroll
    for (int p = 0; p < 8; ++p) {                // 32 rows x 16 cols, coalesced
        int e = p * 64 + l, kk = e >> 4, nn = e & 15;
        S[kk * 16 + nn] = base[(size_t)kk * N + nn];
    }
    asm volatile("s_waitcnt lgkmcnt(0)" ::: "memory");   // wave-internal fence
    __builtin_amdgcn_sched_barrier(0);

    half8 hv;
    #pragma unroll
    for (int j = 0; j < 8; ++j)
        hv[j] = (_Float16)S[((l >> 4) * 8 + j) * 16 + (l & 15)];
    *(half8*)&dst[l * 8] = hv;                   // coalesced 1KB frag store
}

// ---------------------------------------------------------------------------
// Fused QNet: enc (2-layer MLP) + comm + Wc + Wd in one kernel.
// grid 512, block 512 (8 waves, 2/SIMD, 1 block/CU by LDS). Block = 16 batch
// rows x 32 agents; wave w owns agents 4w..4w+3.
// Phase E per agent: obs A-frags global->reg (rows lane-indexed by lm);
//   GEMM1 (B-frags from L2) -> relu -> XS transpose slab -> GEMM2 -> relu ->
//   h into H[row][ag*64+c] (comm layout). One barrier. Then dec's verified
//   comm/Wc/Wd code verbatim (H already populated; no staging).
// ---------------------------------------------------------------------------
extern "C" __global__ __launch_bounds__(512, 2)
void fused_kernel(const float* __restrict__ obs,
                  const float* __restrict__ b1,
                  const float* __restrict__ b2,
                  const float* __restrict__ MnG,
                  const float* __restrict__ bc,
                  const float* __restrict__ bd,
                  const _Float16* __restrict__ W1p,
                  const _Float16* __restrict__ W2p,
                  const _Float16* __restrict__ Wcp,
                  const _Float16* __restrict__ Wdp,
                  float* __restrict__ out)
{
    extern __shared__ char smem[];
    _Float16* H = (_Float16*)smem;                       // 16 x HSTR
    const int t  = threadIdx.x;
    const int b0 = blockIdx.x * 16;
    const int w = t >> 6, l = t & 63, lm = l & 15, lq = l >> 4;
    _Float16* XS = (_Float16*)(smem + 16 * HSTR * 2 + w * FUS_SLAB); // 16x136

    // ================= Phase E: encoder for agents 4w..4w+3 ===============
    #pragma unroll
    for (int g = 0; g < 4; ++g) {
        const int ag = w * 4 + g;
        // A-frags: row (b0+lm), agent ag, 8 k-values per (s, lq)
        const float* ob = obs + (size_t)(b0 + lm) * (NA * NOBS) + ag * NOBS;
        floatx4 a0[4], a1[4];
        #pragma unroll
        for (int s = 0; s < 4; ++s) {
            a0[s] = *(const floatx4*)&ob[s * 32 + lq * 8];
            a1[s] = *(const floatx4*)&ob[s * 32 + lq * 8 + 4];
        }
        half8 af[4];
        #pragma unroll
        for (int s = 0; s < 4; ++s) {
            af[s][0] = (_Float16)a0[s][0]; af[s][1] = (_Float16)a0[s][1];
            af[s][2] = (_Float16)a0[s][2]; af[s][3] = (_Float16)a0[s][3];
            af[s][4] = (_Float16)a1[s][0]; af[s][5] = (_Float16)a1[s][1];
            af[s][6] = (_Float16)a1[s][2]; af[s][7] = (_Float16)a1[s][3];
        }

        // GEMM1: 16x128 @ 128x128 (8 n-tiles), B-frags streamed from L2
        floatx4 acc1[8];
        #pragma unroll
        for (int nt = 0; nt < 8; ++nt) acc1[nt] = (floatx4){0.f, 0.f, 0.f, 0.f};
        #pragma unroll
        for (int s = 0; s < 4; ++s) {
            #pragma unroll
            for (int nt = 0; nt < 8; ++nt) {
                half8 bf = *(const half8*)&W1p[(((ag * 8 + nt) * 4 + s) * 512) + l * 8];
                acc1[nt] = MFMA16(af[s], bf, acc1[nt]);
            }
        }
        // relu + transpose via XS (wave-private slab, reused across agents;
        // wave-internal WAR/RAW -> compiler lgkmcnt)
        #pragma unroll
        for (int nt = 0; nt < 8; ++nt) {
            float bv = b1[ag * NH1 + nt * 16 + lm];
            #pragma unroll
            for (int v = 0; v < 4; ++v)
                XS[(lq * 4 + v) * 136 + nt * 16 + lm] =
                    (_Float16)fmaxf(acc1[nt][v] + bv, 0.f);
        }

        // GEMM2: 16x128 @ 128x64 (4 n-tiles)
        floatx4 acc2[4];
        #pragma unroll
        for (int nt = 0; nt < 4; ++nt) acc2[nt] = (floatx4){0.f, 0.f, 0.f, 0.f};
        #pragma unroll
        for (int s = 0; s < 4; ++s) {
            half8 af2 = *(const half8*)&XS[lm * 136 + s * 32 + lq * 8];
            #pragma unroll
            for (int nt = 0; nt < 4; ++nt) {
                half8 bf = *(const half8*)&W2p[(((ag * 4 + nt) * 4 + s) * 512) + l * 8];
                acc2[nt] = MFMA16(af2, bf, acc2[nt]);
            }
        }
        // relu + h -> H in comm layout [row][ag*64 + c]
        #pragma unroll
        for (int nt = 0; nt < 4; ++nt) {
            float bv = b2[ag * HXX + nt * 16 + lm];
            #pragma unroll
            for (int v = 0; v < 4; ++v)
                H[(lq * 4 + v) * HSTR + ag * 64 + nt * 16 + lm] =
                    (_Float16)fmaxf(acc2[nt][v] + bv, 0.f);
        }
    }
    __syncthreads();   // all agents' h visible to all waves

    // ================= Phase C/D: dec's verified code =====================
    // comm into A-frag registers (reads ALL rows; barrier after)
    half8 hacc[4][2];
    #pragma unroll
    for (int g = 0; g < 4; ++g)
        #pragma unroll
        for (int sb = 0; sb < 2; ++sb)
            #pragma unroll
            for (int q = 0; q < 8; ++q) hacc[g][sb][q] = (_Float16)0.f;

    #pragma unroll 4
    for (int j = 0; j < NA; ++j) {
        half8 v0 = *(const half8*)&H[lm * HSTR + j * 64 + lq * 8];
        half8 v1 = *(const half8*)&H[lm * HSTR + j * 64 + 32 + lq * 8];
        #pragma unroll
        for (int g = 0; g < 4; ++g) {
            int ag = __builtin_amdgcn_readfirstlane(w * 4 + g);
            _Float16 mh = (_Float16)MnG[ag * NA + j];   // s_load, wave-uniform
            hacc[g][0] += v0 * mh;
            hacc[g][1] += v1 * mh;
        }
    }
    __syncthreads();   // all comm reads done before any h2 overwrite
    // From here each wave touches only its own agents' columns.

    // Wc GEMM per n-tile; h2 kept in C-layout regs
    half4 h2r[4][4];
    #pragma unroll
    for (int nt = 0; nt < 4; ++nt) {
        floatx4 acc[4];
        #pragma unroll
        for (int g = 0; g < 4; ++g) acc[g] = (floatx4){0.f, 0.f, 0.f, 0.f};
        #pragma unroll
        for (int s = 0; s < 4; ++s) {
            #pragma unroll
            for (int g = 0; g < 4; ++g) {
                int ag = w * 4 + g;
                half8 af = (s < 2)
                    ? *(const half8*)&H[lm * HSTR + ag * 64 + s * 32 + lq * 8]
                    : hacc[g][s - 2];
                half8 bf = *(const half8*)&Wcp[(((ag * 4 + nt) * 4 + s) * 512) + l * 8];
                acc[g] = MFMA16(af, bf, acc[g]);
            }
        }
        #pragma unroll
        for (int g = 0; g < 4; ++g) {
            int ag = w * 4 + g;
            float bcv = bc[ag * HXX + nt * 16 + lm];
            #pragma unroll
            for (int v = 0; v < 4; ++v)
                h2r[g][nt][v] = (_Float16)fast_tanh(acc[g][v] + bcv);
        }
    }

    // write h2 over own agents' h (all Wc reads of those columns are done)
    #pragma unroll
    for (int g = 0; g < 4; ++g) {
        int ag = w * 4 + g;
        #pragma unroll
        for (int nt = 0; nt < 4; ++nt)
            #pragma unroll
            for (int v = 0; v < 4; ++v)
                H[(lq * 4 + v) * HSTR + ag * 64 + nt * 16 + lm] = h2r[g][nt][v];
    }
    // wave-internal LDS RAW -> compiler lgkmcnt; no cross-wave access

    // Wd GEMM: K=64, N=16
    floatx4 acc3[4];
    #pragma unroll
    for (int g = 0; g < 4; ++g) acc3[g] = (floatx4){0.f, 0.f, 0.f, 0.f};
    #pragma unroll
    for (int s = 0; s < 2; ++s) {
        #pragma unroll
        for (int g = 0; g < 4; ++g) {
            int ag = w * 4 + g;
            half8 af = *(const half8*)&H[lm * HSTR + ag * 64 + s * 32 + lq * 8];
            half8 bf = *(const half8*)&Wdp[((ag * 2 + s) * 512) + l * 8];
            acc3[g] = MFMA16(af, bf, acc3[g]);
        }
    }

    #pragma unroll
    for (int g = 0; g < 4; ++g) {
        int ag = w * 4 + g;
        float bdv = bd[ag * NACT + lm];
        #pragma unroll
        for (int v = 0; v < 4; ++v) {
            int row = lq * 4 + v;
            out[((size_t)(b0 + row) * NA + ag) * NACT + lm] = acc3[g][v] + bdv;
        }
    }
}

// ---------------------------------------------------------------------------
extern "C" void kernel_launch(void* const* d_in, const int* in_sizes, int n_in,
                              void* d_out, int out_size, void* d_ws, size_t ws_size,
                              hipStream_t stream)
{
    const float* obs = (const float*)d_in[0];
    const float* W1  = (const float*)d_in[1];
    const float* b1  = (const float*)d_in[2];
    const float* W2  = (const float*)d_in[3];
    const float* b2  = (const float*)d_in[4];
    const float* Wc  = (const float*)d_in[7];
    const float* bc  = (const float*)d_in[8];
    const float* Wd  = (const float*)d_in[9];
    const float* bd  = (const float*)d_in[10];
    const int*   cm  = (const int*)d_in[11];

    float*    outp = (float*)d_out;
    _Float16* ws   = (_Float16*)d_ws;

    _Float16* W1p = ws + W1P_OFF;
    _Float16* W2p = ws + W2P_OFF;
    _Float16* Wcp = ws + WCP_OFF;
    _Float16* Wdp = ws + WDP_OFF;
    const float* MnG = (const float*)(ws + MN_OFF);

    hipLaunchKernelGGL(pack_kernel, dim3(PK_BLOCKS), dim3(256), 0, stream,
                       W1, W2, Wc, Wd, cm, ws);

    (void)hipFuncSetAttribute((const void*)fused_kernel,
                              hipFuncAttributeMaxDynamicSharedMemorySize, FUS_LDS);
    hipLaunchKernelGGL(fused_kernel, dim3(NB / 16), dim3(512), FUS_LDS, stream,
                       obs, b1, b2, MnG, bc, bd, W1p, W2p, Wcp, Wdp, outp);
}